// Round 7
// baseline (35.821 us; speedup 1.0000x reference)
//
#include <hip/hip_runtime.h>
#include <hip/hip_bf16.h>

// Problem constants
#define B_    64
#define T_    500
#define DIN   1024
#define DOUT  128
#define EPSV  1e-8f
#define BM    128          // t-rows per block tile
#define BK    64           // k per LDS stage
#define NKC   2            // k-chunks (exact: weighting is linear in h)
#define KCL   (DIN / NKC)  // 512
#define NKT   (KCL / BK)   // 8 K-steps per block
#define TILES 4            // ceil(500/128)
#define NGEMM (B_ * TILES * NKC)   // 512 gemm blocks
#define NNORM 16                   // extra blocks computing scale[]

typedef __attribute__((ext_vector_type(8))) short bf16x8;  // MFMA A/B frag
typedef __attribute__((ext_vector_type(4))) float f32x4;   // MFMA C/D frag

// Workspace layout (byte offsets)
//   wT    : bf16 [DOUT][DIN]                 @ 0        (262144 B)
//   scale : f32  [DOUT]                      @ 262144   (512 B)
//   part  : f32  [B_][TILES][2][NKC][DOUT]   @ 262656   (524288 B)
#define OFF_SCALE 262144
#define OFF_PART  262656

__device__ inline short f2bf(float f) {
    __hip_bfloat16 h = __float2bfloat16(f);
    return __builtin_bit_cast(short, h);
}

// Raw barrier: LDS-drain only. Global loads (to registers) ride across it with
// compiler-emitted COUNTED vmcnt at their consumer — avoids __syncthreads()'s
// unconditional vmcnt(0) drain.
__device__ inline void block_sync_lds() {
    asm volatile("s_waitcnt lgkmcnt(0)" ::: "memory");
    __builtin_amdgcn_s_barrier();
    asm volatile("" ::: "memory");
}

// ---------------- prep: transpose/convert w only ----------------
// 32 blocks x 512 threads = 16384 threads; thread handles 8 k's of one d.
// Each read instruction: 64 lanes -> 64 consecutive d -> coalesced 256B.
// Write: one bf16x8 (16B) per thread, 2KB-strided across lanes (L2 absorbs).
__global__ __launch_bounds__(512) void prep_kernel(
    const float* __restrict__ w, __hip_bfloat16* __restrict__ wT)
{
    int t  = blockIdx.x * 512 + threadIdx.x;
    int d  = t & 127;
    int kq = t >> 7;                 // 0..127 (8-k group)
    float v[8];
#pragma unroll
    for (int m = 0; m < 8; ++m)
        v[m] = w[(size_t)(kq * 8 + m) * DOUT + d];
    bf16x8 o;
#pragma unroll
    for (int m = 0; m < 8; ++m) o[m] = f2bf(v[m]);
    *reinterpret_cast<bf16x8*>(wT + (size_t)d * DIN + kq * 8) = o;
}

// ---------------- main: LDS-staged GEMM + fused weighted time-reduction ----------------
// Blocks 0..511: 64 b x 4 t-tiles x 2 k-chunks; 512 threads = 8 waves (2 wr x 4 wc).
// LDS double-buffered A/B [128][64]bf16, XOR-swizzled. 2 blocks/CU.
// Pipeline: step k: issue loads(k+2) -> compute LDS[k&1] -> cvt+write loads(k+1) -> barrier.
// Epilogue weights 1-beta^(T-t) computed on the fly via exp2/log2 (no wtab).
// Blocks 512..527: compute scale[d] = 1/((sum_k w[k][d]^2 + eps)*T), one d per wave.
__global__ __launch_bounds__(512, 4) void gemm_kernel(
    const float* __restrict__ x, const float* __restrict__ w,
    const float* __restrict__ beta, const __hip_bfloat16* __restrict__ wT,
    float* __restrict__ partials, float* __restrict__ scale)
{
    const int tid  = threadIdx.x;
    const int wid  = tid >> 6;
    const int lane = tid & 63;

    if (blockIdx.x >= NGEMM) {
        // ---- scale computation: one d per wave ----
        int d = (blockIdx.x - NGEMM) * 8 + wid;
        float s = 0.f;
#pragma unroll
        for (int i = 0; i < 16; ++i) {
            float v = w[(size_t)(lane + 64 * i) * DOUT + d];
            s += v * v;
        }
        s += __shfl_xor(s, 1);  s += __shfl_xor(s, 2);  s += __shfl_xor(s, 4);
        s += __shfl_xor(s, 8);  s += __shfl_xor(s, 16); s += __shfl_xor(s, 32);
        if (lane == 0) scale[d] = 1.f / ((s + EPSV) * (float)T_);
        return;
    }

    __shared__ __align__(16) char smem[2 * 32768];  // per buf: A @0 (16KB), B @16KB

    const int wg   = blockIdx.x;
    const int kc   = wg & 1;
    const int tile = (wg >> 1) & 3;
    const int b    = wg >> 3;
    const int t0   = tile * BM;
    const int kbase = kc * KCL;
    const int arow = lane & 15;
    const int kblk = lane >> 4;
    const int wr   = wid >> 2;   // 0..1  (row group of 64)
    const int wc   = wid & 3;    // 0..3  (col group of 32)

    const float* xb = x + (size_t)b * T_ * DIN + kbase;

    // ---- staging geometry (loop-invariant) ----
    const int sr = tid >> 4;     // 0..31 (row within pass)
    const int sc = tid & 15;     // float4 index within row
    const float* ag[4];
    int awoff[4];
#pragma unroll
    for (int p = 0; p < 4; ++p) {
        int row  = p * 32 + sr;
        int trow = t0 + row; if (trow >= T_) trow = T_ - 1;  // clamp; weight=0 kills it
        ag[p] = xb + (size_t)trow * DIN + sc * 4;
        awoff[p] = (row * 128 + sc * 8) ^ ((row & 7) << 4);
    }
    const int bcol = tid >> 2;
    const int bch0 = (tid & 3) * 2;
    const __hip_bfloat16* bg0 = wT + (size_t)bcol * DIN + kbase + bch0 * 8;
    const __hip_bfloat16* bg1 = bg0 + 8;
    const int bwoff0 = (bcol * 128 + bch0 * 16)        ^ ((bcol & 7) << 4);
    const int bwoff1 = (bcol * 128 + (bch0 + 1) * 16)  ^ ((bcol & 7) << 4);

    // fragment read offsets, loop-invariant
    int aro[4][2], bro[2][2];
#pragma unroll
    for (int fm = 0; fm < 4; ++fm)
#pragma unroll
        for (int kk = 0; kk < 2; ++kk) {
            int row = wr * 64 + fm * 16 + arow;
            aro[fm][kk] = (row * 128 + kk * 64 + kblk * 16) ^ ((row & 7) << 4);
        }
#pragma unroll
    for (int fn = 0; fn < 2; ++fn)
#pragma unroll
        for (int kk = 0; kk < 2; ++kk) {
            int col = wc * 32 + fn * 16 + arow;
            bro[fn][kk] = (col * 128 + kk * 64 + kblk * 16) ^ ((col & 7) << 4);
        }

    f32x4 acc[4][2] = {};

    // ---- register-queued pipeline macros (all names static; rule #20) ----
#define DECL_SET(S) float4 S##a0, S##a1, S##a2, S##a3; bf16x8 S##b0, S##b1;
#define LOAD_SET(S, KB) \
    S##a0 = *reinterpret_cast<const float4*>(ag[0] + (KB)); \
    S##a1 = *reinterpret_cast<const float4*>(ag[1] + (KB)); \
    S##a2 = *reinterpret_cast<const float4*>(ag[2] + (KB)); \
    S##a3 = *reinterpret_cast<const float4*>(ag[3] + (KB)); \
    S##b0 = *reinterpret_cast<const bf16x8*>(bg0 + (KB));   \
    S##b1 = *reinterpret_cast<const bf16x8*>(bg1 + (KB));
#define WRITE_SET(S, AB, BB) { \
    short4 h0; h0.x=f2bf(S##a0.x); h0.y=f2bf(S##a0.y); h0.z=f2bf(S##a0.z); h0.w=f2bf(S##a0.w); \
    *reinterpret_cast<short4*>((AB) + awoff[0]) = h0; \
    short4 h1; h1.x=f2bf(S##a1.x); h1.y=f2bf(S##a1.y); h1.z=f2bf(S##a1.z); h1.w=f2bf(S##a1.w); \
    *reinterpret_cast<short4*>((AB) + awoff[1]) = h1; \
    short4 h2; h2.x=f2bf(S##a2.x); h2.y=f2bf(S##a2.y); h2.z=f2bf(S##a2.z); h2.w=f2bf(S##a2.w); \
    *reinterpret_cast<short4*>((AB) + awoff[2]) = h2; \
    short4 h3; h3.x=f2bf(S##a3.x); h3.y=f2bf(S##a3.y); h3.z=f2bf(S##a3.z); h3.w=f2bf(S##a3.w); \
    *reinterpret_cast<short4*>((AB) + awoff[3]) = h3; \
    *reinterpret_cast<bf16x8*>((BB) + bwoff0) = S##b0; \
    *reinterpret_cast<bf16x8*>((BB) + bwoff1) = S##b1; }
#define COMPUTE(AB, BB) { \
    _Pragma("unroll") \
    for (int kk = 0; kk < 2; ++kk) { \
        bf16x8 bf0 = *reinterpret_cast<const bf16x8*>((BB) + bro[0][kk]); \
        bf16x8 bf1 = *reinterpret_cast<const bf16x8*>((BB) + bro[1][kk]); \
        _Pragma("unroll") \
        for (int fm = 0; fm < 4; ++fm) { \
            bf16x8 af = *reinterpret_cast<const bf16x8*>((AB) + aro[fm][kk]); \
            acc[fm][0] = __builtin_amdgcn_mfma_f32_16x16x32_bf16(af, bf0, acc[fm][0], 0, 0, 0); \
            acc[fm][1] = __builtin_amdgcn_mfma_f32_16x16x32_bf16(af, bf1, acc[fm][1], 0, 0, 0); \
        } } }

    DECL_SET(qe_)   // even set
    DECL_SET(qo_)   // odd set

    // ---- prologue: load kt=0 and kt=1; write kt=0 -> LDS0 ----
    LOAD_SET(qe_, 0)
    LOAD_SET(qo_, BK)
    WRITE_SET(qe_, smem, smem + 16384)
    block_sync_lds();

    // ---- main loop, fully unrolled so set selection is static ----
#pragma unroll
    for (int kt = 0; kt < NKT; ++kt) {
        char* Acur = smem + (kt & 1) * 32768;
        char* Bcur = Acur + 16384;
        char* Anxt = smem + ((kt + 1) & 1) * 32768;
        char* Bnxt = Anxt + 16384;

        // issue loads for kt+2 into the set consumed at step kt-1
        if (kt + 2 < NKT) {
            if (kt & 1) { LOAD_SET(qo_, (kt + 2) * BK) }
            else        { LOAD_SET(qe_, (kt + 2) * BK) }
        }

        COMPUTE(Acur, Bcur)

        // convert+write the set for kt+1 (loaded at step kt-1 / prologue)
        if (kt + 1 < NKT) {
            if (kt & 1) { WRITE_SET(qe_, Anxt, Bnxt) }
            else        { WRITE_SET(qo_, Anxt, Bnxt) }
            block_sync_lds();
        }
    }
#undef DECL_SET
#undef LOAD_SET
#undef WRITE_SET
#undef COMPUTE

    // ---- epilogue: weighted reduction, weights 1-beta^(T-t) on the fly ----
    // C frag: col = lane&15, row = (lane>>4)*4 + r  [verified mapping]
    const int col0 = wc * 32 + arow;
    const int col1 = col0 + 16;
    const float lb0 = log2f(beta[col0]);   // beta in [0,1): log2(0) = -inf -> weight 1
    const float lb1 = log2f(beta[col1]);
    float s0 = 0.f, s1 = 0.f;
#pragma unroll
    for (int fm = 0; fm < 4; ++fm) {
#pragma unroll
        for (int r = 0; r < 4; ++r) {
            int t = t0 + wr * 64 + fm * 16 + kblk * 4 + r;
            if (t < T_) {
                float e = (float)(T_ - t);
                s0 += (1.f - exp2f(e * lb0)) * acc[fm][0][r];
                s1 += (1.f - exp2f(e * lb1)) * acc[fm][1][r];
            }
        }
    }
    s0 += __shfl_xor(s0, 16); s0 += __shfl_xor(s0, 32);
    s1 += __shfl_xor(s1, 16); s1 += __shfl_xor(s1, 32);

    if (kblk == 0) {
        float* p = partials + ((((size_t)b * TILES + tile) * 2 + wr) * NKC + kc) * DOUT;
        p[col0] = s0;
        p[col1] = s1;
    }
}

// ---------------- finalize: sum partials, scale, bias ----------------
__global__ __launch_bounds__(256) void finalize_kernel(
    const float* __restrict__ partials, const float* __restrict__ scale,
    const float* __restrict__ bias, float* __restrict__ out)
{
    int i = blockIdx.x * 256 + threadIdx.x;  // 8192 = B_*DOUT
    int b = i >> 7, d = i & 127;
    float s = 0.f;
#pragma unroll
    for (int p = 0; p < TILES * 2 * NKC; ++p)
        s += partials[((size_t)b * TILES * 2 * NKC + p) * DOUT + d];
    out[i] = s * scale[d] - bias[d];
}

extern "C" void kernel_launch(void* const* d_in, const int* in_sizes, int n_in,
                              void* d_out, int out_size, void* d_ws, size_t ws_size,
                              hipStream_t stream) {
    const float* x    = (const float*)d_in[0];  // [64][500][1024]
    const float* w    = (const float*)d_in[1];  // [1024][128]
    const float* beta = (const float*)d_in[2];  // [128]
    const float* bias = (const float*)d_in[3];  // [128]
    float* out = (float*)d_out;                 // [64][128] fp32

    char* ws = (char*)d_ws;
    __hip_bfloat16* wT = (__hip_bfloat16*)(ws);
    float* scale    = (float*)(ws + OFF_SCALE);
    float* partials = (float*)(ws + OFF_PART);

    prep_kernel<<<32, 512, 0, stream>>>(w, wT);
    gemm_kernel<<<NGEMM + NNORM, 512, 0, stream>>>(x, w, beta, wT, partials, scale);
    finalize_kernel<<<(B_ * DOUT) / 256, 256, 0, stream>>>(partials, scale, bias, out);
}

// Round 8
// 34.171 us; speedup vs baseline: 1.0483x; 1.0483x over previous
//
#include <hip/hip_runtime.h>
#include <hip/hip_bf16.h>

// Problem constants
#define B_    64
#define T_    500
#define DIN   1024
#define DOUT  128
#define EPSV  1e-8f
#define BM    128          // t-rows per block tile
#define BK    64           // k per LDS stage
#define NKC   2            // k-chunks (exact: weighting is linear in h)
#define KCL   (DIN / NKC)  // 512
#define NKT   (KCL / BK)   // 8 K-steps per block
#define TILES 4            // ceil(500/128)
#define NGEMM (B_ * TILES * NKC)   // 512 gemm blocks — exactly fills 256 CUs at 2/CU
#define NPREP 32                   // prep blocks (also = norm partial count)

typedef __attribute__((ext_vector_type(8))) short bf16x8;  // MFMA A/B frag
typedef __attribute__((ext_vector_type(4))) float f32x4;   // MFMA C/D frag

// Workspace layout (byte offsets)
//   wT       : bf16 [DOUT][DIN]                 @ 0        (262144 B)
//   normPart : f32  [NPREP][DOUT]               @ 262144   (16384 B)
//   part     : f32  [B_][TILES][2][NKC][DOUT]   @ 278528   (524288 B)
#define OFF_NORM  262144
#define OFF_PART  278528

__device__ inline short f2bf(float f) {
    __hip_bfloat16 h = __float2bfloat16(f);
    return __builtin_bit_cast(short, h);
}

// Raw barrier: LDS-drain only. Global loads (to registers) ride across it with
// compiler-emitted COUNTED vmcnt at their consumer — avoids __syncthreads()'s
// unconditional vmcnt(0) drain.
__device__ inline void block_sync_lds() {
    asm volatile("s_waitcnt lgkmcnt(0)" ::: "memory");
    __builtin_amdgcn_s_barrier();
    asm volatile("" ::: "memory");
}

// ---------------- prep: transpose/convert w + per-block norm partials ----------------
// 32 blocks x 512 threads; thread handles 8 k's of one d (coalesced 256B reads
// across the 64 consecutive-d lanes). Also accumulates sum(w^2) for its 8 k's,
// LDS-reduced to normPart[blk][d] — no atomics, replay-safe, no gemm tail.
__global__ __launch_bounds__(512) void prep_kernel(
    const float* __restrict__ w, __hip_bfloat16* __restrict__ wT,
    float* __restrict__ normPart)
{
    const int tid = threadIdx.x;
    const int blk = blockIdx.x;
    const int t   = blk * 512 + tid;
    const int d   = t & 127;
    const int kq  = t >> 7;                 // global 8-k group, 0..127
    float v[8];
    float ss = 0.f;
#pragma unroll
    for (int m = 0; m < 8; ++m) {
        v[m] = w[(size_t)(kq * 8 + m) * DOUT + d];
        ss += v[m] * v[m];
    }
    bf16x8 o;
#pragma unroll
    for (int m = 0; m < 8; ++m) o[m] = f2bf(v[m]);
    *reinterpret_cast<bf16x8*>(wT + (size_t)d * DIN + kq * 8) = o;

    __shared__ float red[512];
    red[tid] = ss;
    __syncthreads();
    if (tid < 128)
        normPart[blk * DOUT + tid] = red[tid] + red[tid + 128] + red[tid + 256] + red[tid + 384];
}

// ---------------- main: LDS-staged GEMM + fused weighted time-reduction ----------------
// 512 blocks = 64 b x 4 t-tiles x 2 k-chunks; 512 threads = 8 waves (2 wr x 4 wc).
// LDS double-buffered A/B [128][64]bf16, XOR-swizzled. 2 blocks/CU.
// Pipeline: step k: issue loads(k+2) -> compute LDS[k&1] -> cvt+write loads(k+1) -> barrier.
// Epilogue weights 1-beta^(T-t) computed on the fly via exp2/log2.
__global__ __launch_bounds__(512, 4) void gemm_kernel(
    const float* __restrict__ x, const float* __restrict__ beta,
    const __hip_bfloat16* __restrict__ wT, float* __restrict__ partials)
{
    __shared__ __align__(16) char smem[2 * 32768];  // per buf: A @0 (16KB), B @16KB

    const int tid  = threadIdx.x;
    const int wid  = tid >> 6;
    const int lane = tid & 63;
    const int wg   = blockIdx.x;
    const int kc   = wg & 1;
    const int tile = (wg >> 1) & 3;
    const int b    = wg >> 3;
    const int t0   = tile * BM;
    const int kbase = kc * KCL;
    const int arow = lane & 15;
    const int kblk = lane >> 4;
    const int wr   = wid >> 2;   // 0..1  (row group of 64)
    const int wc   = wid & 3;    // 0..3  (col group of 32)

    const float* xb = x + (size_t)b * T_ * DIN + kbase;

    // ---- staging geometry (loop-invariant) ----
    const int sr = tid >> 4;     // 0..31 (row within pass)
    const int sc = tid & 15;     // float4 index within row
    const float* ag[4];
    int awoff[4];
#pragma unroll
    for (int p = 0; p < 4; ++p) {
        int row  = p * 32 + sr;
        int trow = t0 + row; if (trow >= T_) trow = T_ - 1;  // clamp; weight=0 kills it
        ag[p] = xb + (size_t)trow * DIN + sc * 4;
        awoff[p] = (row * 128 + sc * 8) ^ ((row & 7) << 4);
    }
    const int bcol = tid >> 2;
    const int bch0 = (tid & 3) * 2;
    const __hip_bfloat16* bg0 = wT + (size_t)bcol * DIN + kbase + bch0 * 8;
    const __hip_bfloat16* bg1 = bg0 + 8;
    const int bwoff0 = (bcol * 128 + bch0 * 16)        ^ ((bcol & 7) << 4);
    const int bwoff1 = (bcol * 128 + (bch0 + 1) * 16)  ^ ((bcol & 7) << 4);

    // fragment read offsets, loop-invariant
    int aro[4][2], bro[2][2];
#pragma unroll
    for (int fm = 0; fm < 4; ++fm)
#pragma unroll
        for (int kk = 0; kk < 2; ++kk) {
            int row = wr * 64 + fm * 16 + arow;
            aro[fm][kk] = (row * 128 + kk * 64 + kblk * 16) ^ ((row & 7) << 4);
        }
#pragma unroll
    for (int fn = 0; fn < 2; ++fn)
#pragma unroll
        for (int kk = 0; kk < 2; ++kk) {
            int col = wc * 32 + fn * 16 + arow;
            bro[fn][kk] = (col * 128 + kk * 64 + kblk * 16) ^ ((col & 7) << 4);
        }

    f32x4 acc[4][2] = {};

    // ---- register-queued pipeline macros (all names static; rule #20) ----
#define DECL_SET(S) float4 S##a0, S##a1, S##a2, S##a3; bf16x8 S##b0, S##b1;
#define LOAD_SET(S, KB) \
    S##a0 = *reinterpret_cast<const float4*>(ag[0] + (KB)); \
    S##a1 = *reinterpret_cast<const float4*>(ag[1] + (KB)); \
    S##a2 = *reinterpret_cast<const float4*>(ag[2] + (KB)); \
    S##a3 = *reinterpret_cast<const float4*>(ag[3] + (KB)); \
    S##b0 = *reinterpret_cast<const bf16x8*>(bg0 + (KB));   \
    S##b1 = *reinterpret_cast<const bf16x8*>(bg1 + (KB));
#define WRITE_SET(S, AB, BB) { \
    short4 h0; h0.x=f2bf(S##a0.x); h0.y=f2bf(S##a0.y); h0.z=f2bf(S##a0.z); h0.w=f2bf(S##a0.w); \
    *reinterpret_cast<short4*>((AB) + awoff[0]) = h0; \
    short4 h1; h1.x=f2bf(S##a1.x); h1.y=f2bf(S##a1.y); h1.z=f2bf(S##a1.z); h1.w=f2bf(S##a1.w); \
    *reinterpret_cast<short4*>((AB) + awoff[1]) = h1; \
    short4 h2; h2.x=f2bf(S##a2.x); h2.y=f2bf(S##a2.y); h2.z=f2bf(S##a2.z); h2.w=f2bf(S##a2.w); \
    *reinterpret_cast<short4*>((AB) + awoff[2]) = h2; \
    short4 h3; h3.x=f2bf(S##a3.x); h3.y=f2bf(S##a3.y); h3.z=f2bf(S##a3.z); h3.w=f2bf(S##a3.w); \
    *reinterpret_cast<short4*>((AB) + awoff[3]) = h3; \
    *reinterpret_cast<bf16x8*>((BB) + bwoff0) = S##b0; \
    *reinterpret_cast<bf16x8*>((BB) + bwoff1) = S##b1; }
#define COMPUTE(AB, BB) { \
    _Pragma("unroll") \
    for (int kk = 0; kk < 2; ++kk) { \
        bf16x8 bf0 = *reinterpret_cast<const bf16x8*>((BB) + bro[0][kk]); \
        bf16x8 bf1 = *reinterpret_cast<const bf16x8*>((BB) + bro[1][kk]); \
        _Pragma("unroll") \
        for (int fm = 0; fm < 4; ++fm) { \
            bf16x8 af = *reinterpret_cast<const bf16x8*>((AB) + aro[fm][kk]); \
            acc[fm][0] = __builtin_amdgcn_mfma_f32_16x16x32_bf16(af, bf0, acc[fm][0], 0, 0, 0); \
            acc[fm][1] = __builtin_amdgcn_mfma_f32_16x16x32_bf16(af, bf1, acc[fm][1], 0, 0, 0); \
        } } }

    DECL_SET(qe_)   // even set
    DECL_SET(qo_)   // odd set

    // ---- prologue: load kt=0 and kt=1; write kt=0 -> LDS0 ----
    LOAD_SET(qe_, 0)
    LOAD_SET(qo_, BK)
    WRITE_SET(qe_, smem, smem + 16384)
    block_sync_lds();

    // ---- main loop, fully unrolled so set selection is static ----
#pragma unroll
    for (int kt = 0; kt < NKT; ++kt) {
        char* Acur = smem + (kt & 1) * 32768;
        char* Bcur = Acur + 16384;
        char* Anxt = smem + ((kt + 1) & 1) * 32768;
        char* Bnxt = Anxt + 16384;

        // issue loads for kt+2 into the set consumed at step kt-1
        if (kt + 2 < NKT) {
            if (kt & 1) { LOAD_SET(qo_, (kt + 2) * BK) }
            else        { LOAD_SET(qe_, (kt + 2) * BK) }
        }

        COMPUTE(Acur, Bcur)

        // convert+write the set for kt+1 (loaded at step kt-1 / prologue)
        if (kt + 1 < NKT) {
            if (kt & 1) { WRITE_SET(qe_, Anxt, Bnxt) }
            else        { WRITE_SET(qo_, Anxt, Bnxt) }
            block_sync_lds();
        }
    }
#undef DECL_SET
#undef LOAD_SET
#undef WRITE_SET
#undef COMPUTE

    // ---- epilogue: weighted reduction, weights 1-beta^(T-t) on the fly ----
    // C frag: col = lane&15, row = (lane>>4)*4 + r  [verified mapping]
    const int col0 = wc * 32 + arow;
    const int col1 = col0 + 16;
    const float lb0 = log2f(beta[col0]);   // beta in [0,1): log2(0) = -inf -> weight 1
    const float lb1 = log2f(beta[col1]);
    float s0 = 0.f, s1 = 0.f;
#pragma unroll
    for (int fm = 0; fm < 4; ++fm) {
#pragma unroll
        for (int r = 0; r < 4; ++r) {
            int t = t0 + wr * 64 + fm * 16 + kblk * 4 + r;
            if (t < T_) {
                float e = (float)(T_ - t);
                s0 += (1.f - exp2f(e * lb0)) * acc[fm][0][r];
                s1 += (1.f - exp2f(e * lb1)) * acc[fm][1][r];
            }
        }
    }
    s0 += __shfl_xor(s0, 16); s0 += __shfl_xor(s0, 32);
    s1 += __shfl_xor(s1, 16); s1 += __shfl_xor(s1, 32);

    if (kblk == 0) {
        float* p = partials + ((((size_t)b * TILES + tile) * 2 + wr) * NKC + kc) * DOUT;
        p[col0] = s0;
        p[col1] = s1;
    }
}

// ---------------- finalize: norm from partials, sum, scale, bias ----------------
__global__ __launch_bounds__(256) void finalize_kernel(
    const float* __restrict__ partials, const float* __restrict__ normPart,
    const float* __restrict__ bias, float* __restrict__ out)
{
    int i = blockIdx.x * 256 + threadIdx.x;  // 8192 = B_*DOUT
    int b = i >> 7, d = i & 127;
    float nrm = 0.f;
#pragma unroll
    for (int g = 0; g < NPREP; ++g)
        nrm += normPart[g * DOUT + d];
    float scale = 1.f / ((nrm + EPSV) * (float)T_);
    float s = 0.f;
#pragma unroll
    for (int p = 0; p < TILES * 2 * NKC; ++p)
        s += partials[((size_t)b * TILES * 2 * NKC + p) * DOUT + d];
    out[i] = s * scale - bias[d];
}

extern "C" void kernel_launch(void* const* d_in, const int* in_sizes, int n_in,
                              void* d_out, int out_size, void* d_ws, size_t ws_size,
                              hipStream_t stream) {
    const float* x    = (const float*)d_in[0];  // [64][500][1024]
    const float* w    = (const float*)d_in[1];  // [1024][128]
    const float* beta = (const float*)d_in[2];  // [128]
    const float* bias = (const float*)d_in[3];  // [128]
    float* out = (float*)d_out;                 // [64][128] fp32

    char* ws = (char*)d_ws;
    __hip_bfloat16* wT = (__hip_bfloat16*)(ws);
    float* normPart = (float*)(ws + OFF_NORM);
    float* partials = (float*)(ws + OFF_PART);

    prep_kernel<<<NPREP, 512, 0, stream>>>(w, wT, normPart);
    gemm_kernel<<<NGEMM, 512, 0, stream>>>(x, beta, wT, partials);
    finalize_kernel<<<(B_ * DOUT) / 256, 256, 0, stream>>>(partials, normPart, bias, out);
}